// Round 11
// baseline (293.425 us; speedup 1.0000x reference)
//
#include <hip/hip_runtime.h>
#include <stdint.h>

#define D_IN  128
#define D_OUT 64
#define BN_EPS 1e-3f

#define BIN_SHIFT 7
#define BIN_NODES 128          // 1 << BIN_SHIFT
#define BIN_CAP   5120         // LDS sort capacity (mean 4096, +16 sigma)
#define CHUNK     8192         // edges per partition block (391 blocks)
#define MAX_BINS  800
#define LOFF_STRIDE 800        // ints per chunk row in loff table
#define MAX_CHUNKS 400
#define PT_STRIDE 72           // ushorts: gemm epilogue LDS row stride

typedef __attribute__((ext_vector_type(8))) short bf16x8;
typedef __attribute__((ext_vector_type(4))) float f32x4;

__device__ __forceinline__ ushort f32_to_bf16_rne(float f) {
  uint u = __float_as_uint(f);
  u += 0x7FFFu + ((u >> 16) & 1u);
  return (ushort)(u >> 16);
}
__device__ __forceinline__ float bf16_to_f32(ushort h) {
  return __uint_as_float((uint)h << 16);
}

// ------------- GEMM via MFMA: pre16 = bf16(X @ W), bf16 in / fp32 acc -------
// Row-major pre16[row][64ch]: one node = one 128-B cache line (load-bearing
// for the gather; r1: slab layouts over-fetch 4x on random access).
// Epilogue staged through LDS -> full 128-B line stores. Block 0 zeroes stats.
__global__ __launch_bounds__(256) void gemm_mfma_kernel(
    const float* __restrict__ x, const float* __restrict__ W,
    ushort* __restrict__ pre16, float* __restrict__ stats,
    int n_nodes, int n_tiles) {
  __shared__ ushort Wb[D_IN * D_OUT];          // 16 KB bf16 copy of W
  __shared__ ushort ptile[64 * PT_STRIDE];     // 9 KB epilogue staging
  const int t = threadIdx.x;
  if (blockIdx.x == 0 && t < 128) stats[t] = 0.f;
  for (int i = t; i < D_IN * D_OUT; i += 256) Wb[i] = f32_to_bf16_rne(W[i]);
  __syncthreads();

  const int lane = t & 63;
  const int wave = t >> 6;
  const int m = lane & 15;
  const int quad = lane >> 4;

  bf16x8 bfrag[4][4];
#pragma unroll
  for (int nt = 0; nt < 4; ++nt)
#pragma unroll
    for (int s = 0; s < 4; ++s)
#pragma unroll
      for (int j = 0; j < 8; ++j)
        bfrag[nt][s][j] =
            (short)Wb[(32 * s + quad * 8 + j) * D_OUT + nt * 16 + m];

  for (int tile = blockIdx.x; tile < n_tiles; tile += gridDim.x) {
    const int rbase0 = tile * 64;
    const int row = rbase0 + wave * 16 + m;
    const size_t rl = (size_t)min(row, n_nodes - 1);
    f32x4 acc0 = {0.f, 0.f, 0.f, 0.f}, acc1 = {0.f, 0.f, 0.f, 0.f};
    f32x4 acc2 = {0.f, 0.f, 0.f, 0.f}, acc3 = {0.f, 0.f, 0.f, 0.f};
#pragma unroll
    for (int s = 0; s < 4; ++s) {
      const float4 xa = *(const float4*)&x[rl * D_IN + s * 32 + quad * 8];
      const float4 xb = *(const float4*)&x[rl * D_IN + s * 32 + quad * 8 + 4];
      bf16x8 af;
      af[0] = (short)f32_to_bf16_rne(xa.x);
      af[1] = (short)f32_to_bf16_rne(xa.y);
      af[2] = (short)f32_to_bf16_rne(xa.z);
      af[3] = (short)f32_to_bf16_rne(xa.w);
      af[4] = (short)f32_to_bf16_rne(xb.x);
      af[5] = (short)f32_to_bf16_rne(xb.y);
      af[6] = (short)f32_to_bf16_rne(xb.z);
      af[7] = (short)f32_to_bf16_rne(xb.w);
      acc0 = __builtin_amdgcn_mfma_f32_16x16x32_bf16(af, bfrag[0][s], acc0, 0, 0, 0);
      acc1 = __builtin_amdgcn_mfma_f32_16x16x32_bf16(af, bfrag[1][s], acc1, 0, 0, 0);
      acc2 = __builtin_amdgcn_mfma_f32_16x16x32_bf16(af, bfrag[2][s], acc2, 0, 0, 0);
      acc3 = __builtin_amdgcn_mfma_f32_16x16x32_bf16(af, bfrag[3][s], acc3, 0, 0, 0);
    }
    __syncthreads();  // previous tile's ptile reads complete
#pragma unroll
    for (int reg = 0; reg < 4; ++reg) {
      const int lr = wave * 16 + quad * 4 + reg;
      ptile[lr * PT_STRIDE + m]      = f32_to_bf16_rne(acc0[reg]);
      ptile[lr * PT_STRIDE + 16 + m] = f32_to_bf16_rne(acc1[reg]);
      ptile[lr * PT_STRIDE + 32 + m] = f32_to_bf16_rne(acc2[reg]);
      ptile[lr * PT_STRIDE + 48 + m] = f32_to_bf16_rne(acc3[reg]);
    }
    __syncthreads();
    // cooperative write-out: 4 threads per row, 32 B each -> 128-B lines
    {
      const int lr = t >> 2;
      const int sg = t & 3;
      const int r = rbase0 + lr;
      if (r < n_nodes) {
        const uint4* pl = (const uint4*)&ptile[lr * PT_STRIDE + sg * 16];
        uint4* po = (uint4*)&pre16[(size_t)r * D_OUT + sg * 16];
        po[0] = pl[0];
        po[1] = pl[1];
      }
    }
  }
}

// ------- Partition: BLOCK-LOCAL bucket layout (no global cursors) ------------
// r10 ledger model: old partition ~85 us despite ~90 MB traffic (~15 us at BW).
// Diagnosis: phase B = 306K device atomics on 782 hot cursors in lockstep
// (chain depth 391 -> r5's hot-cursor disease) + cross-block interleaved bin
// regions -> partial-line RMW. Fix: each block owns bucket[blk*CHUNK ..
// +CHUNK) and sorts its chunk by bin LOCALLY (LDS histogram -> LDS exclusive
// scan -> scatter). Stores land in the block's private 64-KB window
// (L2-resident while active -> full lines retired, amp ~1.0). Per-block bin
// offsets go to loff[blk][bin] (coalesced row write); gather walks the runs.
// record: w0 = (dst_low7 << 17) | src17 ; w1 = fp32 edge_val
__global__ __launch_bounds__(256) void partition_kernel(
    const float* __restrict__ ev, const int* __restrict__ esrc,
    const int* __restrict__ edst, int* __restrict__ loff_g,
    uint2* __restrict__ bucket, int n_edges, int n_bins) {
  __shared__ int cnt[MAX_BINS];
  __shared__ int loffs[MAX_BINS + 1];
  __shared__ int sdata[256];
  const int t = threadIdx.x;
  const int beg = blockIdx.x * CHUNK;
  const int end = min(beg + CHUNK, n_edges);

  for (int i = t; i < n_bins; i += 256) cnt[i] = 0;
  __syncthreads();

  // phase A: LDS histogram, 4 edges per lane per load
  for (int i = beg + t * 4; i < end; i += 1024) {
    if (i + 3 < end) {
      const int4 d4 = *(const int4*)&edst[i];
      atomicAdd(&cnt[d4.x >> BIN_SHIFT], 1);
      atomicAdd(&cnt[d4.y >> BIN_SHIFT], 1);
      atomicAdd(&cnt[d4.z >> BIN_SHIFT], 1);
      atomicAdd(&cnt[d4.w >> BIN_SHIFT], 1);
    } else {
      for (int k = i; k < end; ++k) atomicAdd(&cnt[edst[k] >> BIN_SHIFT], 1);
    }
  }
  __syncthreads();

  // phase B': LOCAL exclusive scan over n_bins (<=1024 via 4/thread) — no
  // global atomics at all. Also zeroes cnt for reuse as rank cursors.
  {
    const int b4 = t * 4;
    int d0 = 0, d1 = 0, d2 = 0, d3 = 0;
    if (b4 + 0 < n_bins) d0 = cnt[b4 + 0];
    if (b4 + 1 < n_bins) d1 = cnt[b4 + 1];
    if (b4 + 2 < n_bins) d2 = cnt[b4 + 2];
    if (b4 + 3 < n_bins) d3 = cnt[b4 + 3];
    const int s = d0 + d1 + d2 + d3;
    sdata[t] = s;
    __syncthreads();
    for (int off = 1; off < 256; off <<= 1) {
      const int u = (t >= off) ? sdata[t - off] : 0;
      __syncthreads();
      sdata[t] += u;
      __syncthreads();
    }
    int run = sdata[t] - s;
    if (b4 + 0 <= n_bins) loffs[b4 + 0] = run;  run += d0;
    if (b4 + 1 <= n_bins) loffs[b4 + 1] = run;  run += d1;
    if (b4 + 2 <= n_bins) loffs[b4 + 2] = run;  run += d2;
    if (b4 + 3 <= n_bins) loffs[b4 + 3] = run;
    if (b4 + 0 < n_bins) cnt[b4 + 0] = 0;
    if (b4 + 1 < n_bins) cnt[b4 + 1] = 0;
    if (b4 + 2 < n_bins) cnt[b4 + 2] = 0;
    if (b4 + 3 < n_bins) cnt[b4 + 3] = 0;
    if (t == 255) loffs[n_bins] = sdata[255];  // block's edge count
  }
  __syncthreads();

  // publish per-block offsets (coalesced 3.1-KB row)
  for (int i = t; i <= n_bins; i += 256)
    loff_g[blockIdx.x * LOFF_STRIDE + i] = loffs[i];

  // phase C: scatter into the block's PRIVATE region — exact, no bounds check
  for (int i = beg + t * 4; i < end; i += 1024) {
    if (i + 3 < end) {
      const int4 d4 = *(const int4*)&edst[i];
      const int4 s4 = *(const int4*)&esrc[i];
      const float4 v4 = *(const float4*)&ev[i];
#pragma unroll
      for (int k = 0; k < 4; ++k) {
        const int dst = (&d4.x)[k];
        const int bin = dst >> BIN_SHIFT;
        const int r = atomicAdd(&cnt[bin], 1);
        const uint w0 =
            ((uint)(dst & (BIN_NODES - 1)) << 17) | (uint)(&s4.x)[k];
        bucket[beg + loffs[bin] + r] =
            make_uint2(w0, __float_as_uint((&v4.x)[k]));
      }
    } else {
      for (int k = i; k < end; ++k) {
        const int dst = edst[k];
        const int bin = dst >> BIN_SHIFT;
        const int r = atomicAdd(&cnt[bin], 1);
        const uint w0 = ((uint)(dst & (BIN_NODES - 1)) << 17) | (uint)esrc[k];
        bucket[beg + loffs[bin] + r] = make_uint2(w0, __float_as_uint(ev[k]));
      }
    }
  }
}

// ------- Bin sort+gather: run-walk loads + proven LDS sort + gather ----------
// Only the two bucket-read loops changed (run-walk over per-chunk runs via
// 16-lane groups); sort tables, 8-deep half-wave gather, stats: untouched
// (r8 lesson: do not fragment the gather stream). Gather remains near the
// random-line concurrency wall (~1.28M line misses x ~700 ns / ~10K
// outstanding ~= 90 us).
__global__ __launch_bounds__(512) void bin_sort_gather_kernel(
    const ushort* __restrict__ pre16, const uint2* __restrict__ bucket,
    const int* __restrict__ loff_g, float* __restrict__ out,
    float* __restrict__ stats, int n_nodes, int n_chunks, int n_bins) {
  __shared__ uint s_src[BIN_CAP];          // 20.0 KB
  __shared__ ushort s_val[BIN_CAP];        // 10.0 KB
  __shared__ int s_hist[BIN_NODES];
  __shared__ int s_off[BIN_NODES + 1];
  __shared__ int s_cur[BIN_NODES];
  __shared__ int s_rs[MAX_CHUNKS];         // run starts (global rec idx)
  __shared__ int s_re[MAX_CHUNKS];         // run ends

  const int t = threadIdx.x;
  const int bin = blockIdx.x;

  // stage this bin's run table: two adjacent ints per chunk row
  for (int r = t; r < n_chunks; r += 512) {
    const int o0 = loff_g[r * LOFF_STRIDE + bin];
    const int o1 = loff_g[r * LOFF_STRIDE + bin + 1];
    s_rs[r] = r * CHUNK + o0;
    s_re[r] = r * CHUNK + o1;
  }
  if (t < BIN_NODES) s_hist[t] = 0;
  __syncthreads();

  const int g16 = t >> 4;   // 32 groups of 16 lanes walk runs
  const int l16 = t & 15;

  // histogram pass over runs
  for (int rr = g16; rr < n_chunks; rr += 32)
    for (int i = s_rs[rr] + l16; i < s_re[rr]; i += 16)
      atomicAdd(&s_hist[bucket[i].x >> 17], 1);
  __syncthreads();

  int own = (t < BIN_NODES) ? s_hist[t] : 0;
  for (int off = 1; off < BIN_NODES; off <<= 1) {
    int u = 0;
    if (t < BIN_NODES && t >= off) u = s_hist[t - off];
    __syncthreads();
    if (t < BIN_NODES) s_hist[t] += u;
    __syncthreads();
  }
  if (t < BIN_NODES) {
    const int e = s_hist[t] - own;
    s_off[t] = e;
    s_cur[t] = e;
  }
  if (t == 0) s_off[BIN_NODES] = s_hist[BIN_NODES - 1];  // total records
  __syncthreads();

  // scatter pass over runs (BIN_CAP clamp = LDS overflow insurance)
  for (int rr = g16; rr < n_chunks; rr += 32)
    for (int i = s_rs[rr] + l16; i < s_re[rr]; i += 16) {
      const uint2 r = bucket[i];
      const int d = r.x >> 17;
      const int p = atomicAdd(&s_cur[d], 1);
      if (p < BIN_CAP) {
        s_src[p] = r.x & 0x1FFFFu;
        s_val[p] = f32_to_bf16_rne(__uint_as_float(r.y));
      }
    }
  __syncthreads();

  // gather: wave per node (8 waves); half-waves on even/odd records;
  // 8 records/half in flight in main loop. UNCHANGED.
  const int lane = t & 63;
  const int wave = t >> 6;
  const int half = lane >> 5;
  const int hl = lane & 31;
  const int node0 = bin * BIN_NODES;
  float csx = 0.f, csy = 0.f, cs2x = 0.f, cs2y = 0.f;

  for (int nl = wave; nl < BIN_NODES; nl += 8) {
    const int node = node0 + nl;
    if (node < n_nodes) {
      const int jb = min(s_off[nl], BIN_CAP);
      const int je = min(s_off[nl + 1], BIN_CAP);
      float a0x = 0.f, a0y = 0.f, a1x = 0.f, a1y = 0.f;
      float a2x = 0.f, a2y = 0.f, a3x = 0.f, a3y = 0.f;
      float a4x = 0.f, a4y = 0.f, a5x = 0.f, a5y = 0.f;
      float a6x = 0.f, a6y = 0.f, a7x = 0.f, a7y = 0.f;
      int j = jb + half;
      // main: 16 records per wave-iteration, 8 loads in flight per half
      for (; j + 14 < je; j += 16) {
        const uint src0 = s_src[j],      src1 = s_src[j + 2];
        const uint src2 = s_src[j + 4],  src3 = s_src[j + 6];
        const uint src4 = s_src[j + 8],  src5 = s_src[j + 10];
        const uint src6 = s_src[j + 12], src7 = s_src[j + 14];
        const float v0 = bf16_to_f32(s_val[j]);
        const float v1 = bf16_to_f32(s_val[j + 2]);
        const float v2 = bf16_to_f32(s_val[j + 4]);
        const float v3 = bf16_to_f32(s_val[j + 6]);
        const float v4 = bf16_to_f32(s_val[j + 8]);
        const float v5 = bf16_to_f32(s_val[j + 10]);
        const float v6 = bf16_to_f32(s_val[j + 12]);
        const float v7 = bf16_to_f32(s_val[j + 14]);
        const uint p0 = *(const uint*)&pre16[(size_t)src0 * D_OUT + 2 * hl];
        const uint p1 = *(const uint*)&pre16[(size_t)src1 * D_OUT + 2 * hl];
        const uint p2 = *(const uint*)&pre16[(size_t)src2 * D_OUT + 2 * hl];
        const uint p3 = *(const uint*)&pre16[(size_t)src3 * D_OUT + 2 * hl];
        const uint p4 = *(const uint*)&pre16[(size_t)src4 * D_OUT + 2 * hl];
        const uint p5 = *(const uint*)&pre16[(size_t)src5 * D_OUT + 2 * hl];
        const uint p6 = *(const uint*)&pre16[(size_t)src6 * D_OUT + 2 * hl];
        const uint p7 = *(const uint*)&pre16[(size_t)src7 * D_OUT + 2 * hl];
        a0x += v0 * bf16_to_f32((ushort)(p0 & 0xFFFFu));
        a0y += v0 * bf16_to_f32((ushort)(p0 >> 16));
        a1x += v1 * bf16_to_f32((ushort)(p1 & 0xFFFFu));
        a1y += v1 * bf16_to_f32((ushort)(p1 >> 16));
        a2x += v2 * bf16_to_f32((ushort)(p2 & 0xFFFFu));
        a2y += v2 * bf16_to_f32((ushort)(p2 >> 16));
        a3x += v3 * bf16_to_f32((ushort)(p3 & 0xFFFFu));
        a3y += v3 * bf16_to_f32((ushort)(p3 >> 16));
        a4x += v4 * bf16_to_f32((ushort)(p4 & 0xFFFFu));
        a4y += v4 * bf16_to_f32((ushort)(p4 >> 16));
        a5x += v5 * bf16_to_f32((ushort)(p5 & 0xFFFFu));
        a5y += v5 * bf16_to_f32((ushort)(p5 >> 16));
        a6x += v6 * bf16_to_f32((ushort)(p6 & 0xFFFFu));
        a6y += v6 * bf16_to_f32((ushort)(p6 >> 16));
        a7x += v7 * bf16_to_f32((ushort)(p7 & 0xFFFFu));
        a7y += v7 * bf16_to_f32((ushort)(p7 >> 16));
      }
      // mid: 8 records per wave-iteration
      for (; j + 6 < je; j += 8) {
        const uint src0 = s_src[j],     src1 = s_src[j + 2];
        const uint src2 = s_src[j + 4], src3 = s_src[j + 6];
        const float v0 = bf16_to_f32(s_val[j]);
        const float v1 = bf16_to_f32(s_val[j + 2]);
        const float v2 = bf16_to_f32(s_val[j + 4]);
        const float v3 = bf16_to_f32(s_val[j + 6]);
        const uint p0 = *(const uint*)&pre16[(size_t)src0 * D_OUT + 2 * hl];
        const uint p1 = *(const uint*)&pre16[(size_t)src1 * D_OUT + 2 * hl];
        const uint p2 = *(const uint*)&pre16[(size_t)src2 * D_OUT + 2 * hl];
        const uint p3 = *(const uint*)&pre16[(size_t)src3 * D_OUT + 2 * hl];
        a0x += v0 * bf16_to_f32((ushort)(p0 & 0xFFFFu));
        a0y += v0 * bf16_to_f32((ushort)(p0 >> 16));
        a1x += v1 * bf16_to_f32((ushort)(p1 & 0xFFFFu));
        a1y += v1 * bf16_to_f32((ushort)(p1 >> 16));
        a2x += v2 * bf16_to_f32((ushort)(p2 & 0xFFFFu));
        a2y += v2 * bf16_to_f32((ushort)(p2 >> 16));
        a3x += v3 * bf16_to_f32((ushort)(p3 & 0xFFFFu));
        a3y += v3 * bf16_to_f32((ushort)(p3 >> 16));
      }
      for (; j < je; j += 2) {
        const uint src = s_src[j];
        const float v = bf16_to_f32(s_val[j]);
        const uint p = *(const uint*)&pre16[(size_t)src * D_OUT + 2 * hl];
        a0x += v * bf16_to_f32((ushort)(p & 0xFFFFu));
        a0y += v * bf16_to_f32((ushort)(p >> 16));
      }
      float ax = ((a0x + a1x) + (a2x + a3x)) + ((a4x + a5x) + (a6x + a7x));
      float ay = ((a0y + a1y) + (a2y + a3y)) + ((a4y + a5y) + (a6y + a7y));
      ax += __shfl_xor(ax, 32);   // merge odd-record half into even half
      ay += __shfl_xor(ay, 32);
      if (half == 0) {
        *(float2*)&out[(size_t)node * D_OUT + 2 * hl] = make_float2(ax, ay);
        csx += ax;
        cs2x += ax * ax;
        csy += ay;
        cs2y += ay * ay;
      }
    }
  }
  __syncthreads();  // record reads done; alias reduction buffers onto s_src

  float* red = (float*)s_src;       // [8 waves][64 cols] sums (2 KB)
  float* red2 = red + 512;          // [8 waves][64 cols] sumsq (2 KB)
  if (half == 0) {
    red[wave * 64 + 2 * hl] = csx;
    red[wave * 64 + 2 * hl + 1] = csy;
    red2[wave * 64 + 2 * hl] = cs2x;
    red2[wave * 64 + 2 * hl + 1] = cs2y;
  }
  __syncthreads();
  if (t < 64) {
    float s = 0.f, s2 = 0.f;
#pragma unroll
    for (int wv = 0; wv < 8; ++wv) {
      s += red[wv * 64 + t];
      s2 += red2[wv * 64 + t];
    }
    atomicAdd(&stats[t], s);
    atomicAdd(&stats[64 + t], s2);
  }
}

// ---------------- Normalize + ReLU (in place, float4) ----------------
__global__ __launch_bounds__(256) void norm_kernel(
    float* __restrict__ out, const float* __restrict__ stats, int64_t n_vec4,
    float inv_n) {
  const int c = (threadIdx.x * 4) & 63;
  float mean[4], scale[4];
#pragma unroll
  for (int k = 0; k < 4; ++k) {
    mean[k] = stats[c + k] * inv_n;
    const float var = stats[64 + c + k] * inv_n - mean[k] * mean[k];
    scale[k] = rsqrtf(var + BN_EPS);
  }
  const int64_t stride = (int64_t)gridDim.x * 256;
  for (int64_t i = (int64_t)blockIdx.x * 256 + threadIdx.x; i < n_vec4;
       i += stride) {
    float4 v = ((float4*)out)[i];
    v.x = (v.x - mean[0]) * scale[0];
    v.y = (v.y - mean[1]) * scale[1];
    v.z = (v.z - mean[2]) * scale[2];
    v.w = (v.w - mean[3]) * scale[3];
    v.x = v.x > 0.f ? v.x : 0.f;
    v.y = v.y > 0.f ? v.y : 0.f;
    v.z = v.z > 0.f ? v.z : 0.f;
    v.w = v.w > 0.f ? v.w : 0.f;
    ((float4*)out)[i] = v;
  }
}

// ---------------- launch: 4 dispatches total ----------------
extern "C" void kernel_launch(void* const* d_in, const int* in_sizes, int n_in,
                              void* d_out, int out_size, void* d_ws,
                              size_t ws_size, hipStream_t stream) {
  const float* x = (const float*)d_in[0];
  const float* W = (const float*)d_in[1];
  const float* ev = (const float*)d_in[2];
  const int* esrc = (const int*)d_in[3];
  const int* edst = (const int*)d_in[4];

  const int n_nodes = in_sizes[0] / D_IN;
  const int n_edges = in_sizes[2];
  const int64_t n_out = (int64_t)n_nodes * D_OUT;
  const int n_bins = (n_nodes + BIN_NODES - 1) >> BIN_SHIFT;
  const int n_row_tiles = (n_nodes + 63) / 64;
  const int n_chunks = (n_edges + CHUNK - 1) / CHUNK;

  float* out = (float*)d_out;

  // workspace layout (~40 MB total, under prior peaks)
  char* w = (char*)d_ws;
  ushort* pre16 = (ushort*)w;             w += (size_t)n_nodes * D_OUT * 2;
  float* stats = (float*)w;               w += 128 * 4;
  int* loff_g = (int*)w;                  w += (size_t)n_chunks * LOFF_STRIDE * 4;
  w = (char*)(((uintptr_t)w + 7) & ~(uintptr_t)7);
  uint2* bucket = (uint2*)w;              // n_edges * 8 bytes (25.6 MB, exact)

  gemm_mfma_kernel<<<(n_row_tiles + 1) / 2, 256, 0, stream>>>(
      x, W, pre16, stats, n_nodes, n_row_tiles);
  partition_kernel<<<n_chunks, 256, 0, stream>>>(ev, esrc, edst, loff_g,
                                                 bucket, n_edges, n_bins);
  bin_sort_gather_kernel<<<n_bins, 512, 0, stream>>>(
      pre16, bucket, loff_g, out, stats, n_nodes, n_chunks, n_bins);
  norm_kernel<<<2048, 256, 0, stream>>>(out, stats, n_out / 4,
                                        1.0f / (float)n_nodes);
}

// Round 12
// 284.805 us; speedup vs baseline: 1.0303x; 1.0303x over previous
//
#include <hip/hip_runtime.h>
#include <stdint.h>

#define D_IN  128
#define D_OUT 64
#define BN_EPS 1e-3f

#define BIN_SHIFT 7
#define BIN_NODES 128          // 1 << BIN_SHIFT
#define BIN_CAP   5120         // LDS sort capacity (mean 4096, +16 sigma)
#define CHUNK     8192         // edges per partition block (391 blocks)
#define MAX_BINS  800
#define LOFF_STRIDE 800        // ints per chunk row in loff table
#define MAX_CHUNKS 400
#define PT_STRIDE 72           // ushorts: gemm epilogue LDS row stride

typedef __attribute__((ext_vector_type(8))) short bf16x8;
typedef __attribute__((ext_vector_type(4))) float f32x4;

__device__ __forceinline__ ushort f32_to_bf16_rne(float f) {
  uint u = __float_as_uint(f);
  u += 0x7FFFu + ((u >> 16) & 1u);
  return (ushort)(u >> 16);
}
__device__ __forceinline__ float bf16_to_f32(ushort h) {
  return __uint_as_float((uint)h << 16);
}

// ------------- GEMM via MFMA: pre16 = bf16(X @ W), bf16 in / fp32 acc -------
// Row-major pre16[row][64ch]: one node = one 128-B cache line (load-bearing
// for the gather; r1: slab layouts over-fetch 4x on random access).
// Epilogue staged through LDS -> full 128-B line stores. Block 0 zeroes stats.
// Grid = n_row_tiles (1 tile/block): streaming kernels need waves — at 782
// blocks this ran at 3 waves/SIMD (r12 occupancy theory).
__global__ __launch_bounds__(256) void gemm_mfma_kernel(
    const float* __restrict__ x, const float* __restrict__ W,
    ushort* __restrict__ pre16, float* __restrict__ stats,
    int n_nodes, int n_tiles) {
  __shared__ ushort Wb[D_IN * D_OUT];          // 16 KB bf16 copy of W
  __shared__ ushort ptile[64 * PT_STRIDE];     // 9 KB epilogue staging
  const int t = threadIdx.x;
  if (blockIdx.x == 0 && t < 128) stats[t] = 0.f;
  for (int i = t; i < D_IN * D_OUT; i += 256) Wb[i] = f32_to_bf16_rne(W[i]);
  __syncthreads();

  const int lane = t & 63;
  const int wave = t >> 6;
  const int m = lane & 15;
  const int quad = lane >> 4;

  bf16x8 bfrag[4][4];
#pragma unroll
  for (int nt = 0; nt < 4; ++nt)
#pragma unroll
    for (int s = 0; s < 4; ++s)
#pragma unroll
      for (int j = 0; j < 8; ++j)
        bfrag[nt][s][j] =
            (short)Wb[(32 * s + quad * 8 + j) * D_OUT + nt * 16 + m];

  for (int tile = blockIdx.x; tile < n_tiles; tile += gridDim.x) {
    const int rbase0 = tile * 64;
    const int row = rbase0 + wave * 16 + m;
    const size_t rl = (size_t)min(row, n_nodes - 1);
    f32x4 acc0 = {0.f, 0.f, 0.f, 0.f}, acc1 = {0.f, 0.f, 0.f, 0.f};
    f32x4 acc2 = {0.f, 0.f, 0.f, 0.f}, acc3 = {0.f, 0.f, 0.f, 0.f};
#pragma unroll
    for (int s = 0; s < 4; ++s) {
      const float4 xa = *(const float4*)&x[rl * D_IN + s * 32 + quad * 8];
      const float4 xb = *(const float4*)&x[rl * D_IN + s * 32 + quad * 8 + 4];
      bf16x8 af;
      af[0] = (short)f32_to_bf16_rne(xa.x);
      af[1] = (short)f32_to_bf16_rne(xa.y);
      af[2] = (short)f32_to_bf16_rne(xa.z);
      af[3] = (short)f32_to_bf16_rne(xa.w);
      af[4] = (short)f32_to_bf16_rne(xb.x);
      af[5] = (short)f32_to_bf16_rne(xb.y);
      af[6] = (short)f32_to_bf16_rne(xb.z);
      af[7] = (short)f32_to_bf16_rne(xb.w);
      acc0 = __builtin_amdgcn_mfma_f32_16x16x32_bf16(af, bfrag[0][s], acc0, 0, 0, 0);
      acc1 = __builtin_amdgcn_mfma_f32_16x16x32_bf16(af, bfrag[1][s], acc1, 0, 0, 0);
      acc2 = __builtin_amdgcn_mfma_f32_16x16x32_bf16(af, bfrag[2][s], acc2, 0, 0, 0);
      acc3 = __builtin_amdgcn_mfma_f32_16x16x32_bf16(af, bfrag[3][s], acc3, 0, 0, 0);
    }
    __syncthreads();  // previous tile's ptile reads complete
#pragma unroll
    for (int reg = 0; reg < 4; ++reg) {
      const int lr = wave * 16 + quad * 4 + reg;
      ptile[lr * PT_STRIDE + m]      = f32_to_bf16_rne(acc0[reg]);
      ptile[lr * PT_STRIDE + 16 + m] = f32_to_bf16_rne(acc1[reg]);
      ptile[lr * PT_STRIDE + 32 + m] = f32_to_bf16_rne(acc2[reg]);
      ptile[lr * PT_STRIDE + 48 + m] = f32_to_bf16_rne(acc3[reg]);
    }
    __syncthreads();
    // cooperative write-out: 4 threads per row, 32 B each -> 128-B lines
    {
      const int lr = t >> 2;
      const int sg = t & 3;
      const int r = rbase0 + lr;
      if (r < n_nodes) {
        const uint4* pl = (const uint4*)&ptile[lr * PT_STRIDE + sg * 16];
        uint4* po = (uint4*)&pre16[(size_t)r * D_OUT + sg * 16];
        po[0] = pl[0];
        po[1] = pl[1];
      }
    }
  }
}

// ------- Partition: block-local bucket layout, 1024 threads ------------------
// Algorithm identical to r11 (LDS histogram -> local exclusive scan -> scatter
// into the block's private 64-KB bucket window; no global cursors; amp ~1.0
// writes). Launch-shape fix (r12): at 256 threads this kernel ran 1564 waves
// on 1024 SIMDs = 1.5 waves/SIMD — latency-starved streaming. 1024 threads ->
// 16 waves/block, ~6.1 waves/SIMD at the same 391 blocks.
// record: w0 = (dst_low7 << 17) | src17 ; w1 = fp32 edge_val
__global__ __launch_bounds__(1024) void partition_kernel(
    const float* __restrict__ ev, const int* __restrict__ esrc,
    const int* __restrict__ edst, int* __restrict__ loff_g,
    uint2* __restrict__ bucket, int n_edges, int n_bins) {
  __shared__ int cnt[MAX_BINS];
  __shared__ int loffs[MAX_BINS + 1];
  __shared__ int sdata[1024];
  const int t = threadIdx.x;
  const int beg = blockIdx.x * CHUNK;
  const int end = min(beg + CHUNK, n_edges);

  for (int i = t; i < n_bins; i += 1024) cnt[i] = 0;
  __syncthreads();

  // phase A: LDS histogram, 4 edges per lane per load
  for (int i = beg + t * 4; i < end; i += 4096) {
    if (i + 3 < end) {
      const int4 d4 = *(const int4*)&edst[i];
      atomicAdd(&cnt[d4.x >> BIN_SHIFT], 1);
      atomicAdd(&cnt[d4.y >> BIN_SHIFT], 1);
      atomicAdd(&cnt[d4.z >> BIN_SHIFT], 1);
      atomicAdd(&cnt[d4.w >> BIN_SHIFT], 1);
    } else {
      for (int k = i; k < end; ++k) atomicAdd(&cnt[edst[k] >> BIN_SHIFT], 1);
    }
  }
  __syncthreads();

  // phase B': local exclusive scan, 1 bin/thread (n_bins <= 1024); zeroes cnt
  {
    const int v = (t < n_bins) ? cnt[t] : 0;
    sdata[t] = v;
    __syncthreads();
    for (int off = 1; off < 1024; off <<= 1) {
      const int u = (t >= off) ? sdata[t - off] : 0;
      __syncthreads();
      sdata[t] += u;
      __syncthreads();
    }
    if (t < n_bins) {
      loffs[t] = sdata[t] - v;
      cnt[t] = 0;  // reuse as rank cursor
    }
    if (t == n_bins - 1) loffs[n_bins] = sdata[t];
  }
  __syncthreads();

  // publish per-block offsets (coalesced row)
  for (int i = t; i <= n_bins; i += 1024)
    loff_g[blockIdx.x * LOFF_STRIDE + i] = loffs[i];

  // phase C: scatter into the block's PRIVATE region — exact, no bounds check
  for (int i = beg + t * 4; i < end; i += 4096) {
    if (i + 3 < end) {
      const int4 d4 = *(const int4*)&edst[i];
      const int4 s4 = *(const int4*)&esrc[i];
      const float4 v4 = *(const float4*)&ev[i];
#pragma unroll
      for (int k = 0; k < 4; ++k) {
        const int dst = (&d4.x)[k];
        const int bin = dst >> BIN_SHIFT;
        const int r = atomicAdd(&cnt[bin], 1);
        const uint w0 =
            ((uint)(dst & (BIN_NODES - 1)) << 17) | (uint)(&s4.x)[k];
        bucket[beg + loffs[bin] + r] =
            make_uint2(w0, __float_as_uint((&v4.x)[k]));
      }
    } else {
      for (int k = i; k < end; ++k) {
        const int dst = edst[k];
        const int bin = dst >> BIN_SHIFT;
        const int r = atomicAdd(&cnt[bin], 1);
        const uint w0 = ((uint)(dst & (BIN_NODES - 1)) << 17) | (uint)esrc[k];
        bucket[beg + loffs[bin] + r] = make_uint2(w0, __float_as_uint(ev[k]));
      }
    }
  }
}

// ------- Bin sort+gather: run-walk loads + proven LDS sort + gather ----------
// Unchanged from r11. Run-walk reads cost ~13 us of fragmentation (FETCH
// 155->207 MB) but enable the no-global-cursor partition; gather core remains
// at the random-line concurrency wall (~1.28M line misses x ~700 ns / ~10K
// outstanding ~= 90 us; r8 lesson: do not fragment the gather stream).
__global__ __launch_bounds__(512) void bin_sort_gather_kernel(
    const ushort* __restrict__ pre16, const uint2* __restrict__ bucket,
    const int* __restrict__ loff_g, float* __restrict__ out,
    float* __restrict__ stats, int n_nodes, int n_chunks, int n_bins) {
  __shared__ uint s_src[BIN_CAP];          // 20.0 KB
  __shared__ ushort s_val[BIN_CAP];        // 10.0 KB
  __shared__ int s_hist[BIN_NODES];
  __shared__ int s_off[BIN_NODES + 1];
  __shared__ int s_cur[BIN_NODES];
  __shared__ int s_rs[MAX_CHUNKS];         // run starts (global rec idx)
  __shared__ int s_re[MAX_CHUNKS];         // run ends

  const int t = threadIdx.x;
  const int bin = blockIdx.x;

  // stage this bin's run table: two adjacent ints per chunk row
  for (int r = t; r < n_chunks; r += 512) {
    const int o0 = loff_g[r * LOFF_STRIDE + bin];
    const int o1 = loff_g[r * LOFF_STRIDE + bin + 1];
    s_rs[r] = r * CHUNK + o0;
    s_re[r] = r * CHUNK + o1;
  }
  if (t < BIN_NODES) s_hist[t] = 0;
  __syncthreads();

  const int g16 = t >> 4;   // 32 groups of 16 lanes walk runs
  const int l16 = t & 15;

  // histogram pass over runs
  for (int rr = g16; rr < n_chunks; rr += 32)
    for (int i = s_rs[rr] + l16; i < s_re[rr]; i += 16)
      atomicAdd(&s_hist[bucket[i].x >> 17], 1);
  __syncthreads();

  int own = (t < BIN_NODES) ? s_hist[t] : 0;
  for (int off = 1; off < BIN_NODES; off <<= 1) {
    int u = 0;
    if (t < BIN_NODES && t >= off) u = s_hist[t - off];
    __syncthreads();
    if (t < BIN_NODES) s_hist[t] += u;
    __syncthreads();
  }
  if (t < BIN_NODES) {
    const int e = s_hist[t] - own;
    s_off[t] = e;
    s_cur[t] = e;
  }
  if (t == 0) s_off[BIN_NODES] = s_hist[BIN_NODES - 1];  // total records
  __syncthreads();

  // scatter pass over runs (BIN_CAP clamp = LDS overflow insurance)
  for (int rr = g16; rr < n_chunks; rr += 32)
    for (int i = s_rs[rr] + l16; i < s_re[rr]; i += 16) {
      const uint2 r = bucket[i];
      const int d = r.x >> 17;
      const int p = atomicAdd(&s_cur[d], 1);
      if (p < BIN_CAP) {
        s_src[p] = r.x & 0x1FFFFu;
        s_val[p] = f32_to_bf16_rne(__uint_as_float(r.y));
      }
    }
  __syncthreads();

  // gather: wave per node (8 waves); half-waves on even/odd records;
  // 8 records/half in flight in main loop. UNCHANGED.
  const int lane = t & 63;
  const int wave = t >> 6;
  const int half = lane >> 5;
  const int hl = lane & 31;
  const int node0 = bin * BIN_NODES;
  float csx = 0.f, csy = 0.f, cs2x = 0.f, cs2y = 0.f;

  for (int nl = wave; nl < BIN_NODES; nl += 8) {
    const int node = node0 + nl;
    if (node < n_nodes) {
      const int jb = min(s_off[nl], BIN_CAP);
      const int je = min(s_off[nl + 1], BIN_CAP);
      float a0x = 0.f, a0y = 0.f, a1x = 0.f, a1y = 0.f;
      float a2x = 0.f, a2y = 0.f, a3x = 0.f, a3y = 0.f;
      float a4x = 0.f, a4y = 0.f, a5x = 0.f, a5y = 0.f;
      float a6x = 0.f, a6y = 0.f, a7x = 0.f, a7y = 0.f;
      int j = jb + half;
      // main: 16 records per wave-iteration, 8 loads in flight per half
      for (; j + 14 < je; j += 16) {
        const uint src0 = s_src[j],      src1 = s_src[j + 2];
        const uint src2 = s_src[j + 4],  src3 = s_src[j + 6];
        const uint src4 = s_src[j + 8],  src5 = s_src[j + 10];
        const uint src6 = s_src[j + 12], src7 = s_src[j + 14];
        const float v0 = bf16_to_f32(s_val[j]);
        const float v1 = bf16_to_f32(s_val[j + 2]);
        const float v2 = bf16_to_f32(s_val[j + 4]);
        const float v3 = bf16_to_f32(s_val[j + 6]);
        const float v4 = bf16_to_f32(s_val[j + 8]);
        const float v5 = bf16_to_f32(s_val[j + 10]);
        const float v6 = bf16_to_f32(s_val[j + 12]);
        const float v7 = bf16_to_f32(s_val[j + 14]);
        const uint p0 = *(const uint*)&pre16[(size_t)src0 * D_OUT + 2 * hl];
        const uint p1 = *(const uint*)&pre16[(size_t)src1 * D_OUT + 2 * hl];
        const uint p2 = *(const uint*)&pre16[(size_t)src2 * D_OUT + 2 * hl];
        const uint p3 = *(const uint*)&pre16[(size_t)src3 * D_OUT + 2 * hl];
        const uint p4 = *(const uint*)&pre16[(size_t)src4 * D_OUT + 2 * hl];
        const uint p5 = *(const uint*)&pre16[(size_t)src5 * D_OUT + 2 * hl];
        const uint p6 = *(const uint*)&pre16[(size_t)src6 * D_OUT + 2 * hl];
        const uint p7 = *(const uint*)&pre16[(size_t)src7 * D_OUT + 2 * hl];
        a0x += v0 * bf16_to_f32((ushort)(p0 & 0xFFFFu));
        a0y += v0 * bf16_to_f32((ushort)(p0 >> 16));
        a1x += v1 * bf16_to_f32((ushort)(p1 & 0xFFFFu));
        a1y += v1 * bf16_to_f32((ushort)(p1 >> 16));
        a2x += v2 * bf16_to_f32((ushort)(p2 & 0xFFFFu));
        a2y += v2 * bf16_to_f32((ushort)(p2 >> 16));
        a3x += v3 * bf16_to_f32((ushort)(p3 & 0xFFFFu));
        a3y += v3 * bf16_to_f32((ushort)(p3 >> 16));
        a4x += v4 * bf16_to_f32((ushort)(p4 & 0xFFFFu));
        a4y += v4 * bf16_to_f32((ushort)(p4 >> 16));
        a5x += v5 * bf16_to_f32((ushort)(p5 & 0xFFFFu));
        a5y += v5 * bf16_to_f32((ushort)(p5 >> 16));
        a6x += v6 * bf16_to_f32((ushort)(p6 & 0xFFFFu));
        a6y += v6 * bf16_to_f32((ushort)(p6 >> 16));
        a7x += v7 * bf16_to_f32((ushort)(p7 & 0xFFFFu));
        a7y += v7 * bf16_to_f32((ushort)(p7 >> 16));
      }
      // mid: 8 records per wave-iteration
      for (; j + 6 < je; j += 8) {
        const uint src0 = s_src[j],     src1 = s_src[j + 2];
        const uint src2 = s_src[j + 4], src3 = s_src[j + 6];
        const float v0 = bf16_to_f32(s_val[j]);
        const float v1 = bf16_to_f32(s_val[j + 2]);
        const float v2 = bf16_to_f32(s_val[j + 4]);
        const float v3 = bf16_to_f32(s_val[j + 6]);
        const uint p0 = *(const uint*)&pre16[(size_t)src0 * D_OUT + 2 * hl];
        const uint p1 = *(const uint*)&pre16[(size_t)src1 * D_OUT + 2 * hl];
        const uint p2 = *(const uint*)&pre16[(size_t)src2 * D_OUT + 2 * hl];
        const uint p3 = *(const uint*)&pre16[(size_t)src3 * D_OUT + 2 * hl];
        a0x += v0 * bf16_to_f32((ushort)(p0 & 0xFFFFu));
        a0y += v0 * bf16_to_f32((ushort)(p0 >> 16));
        a1x += v1 * bf16_to_f32((ushort)(p1 & 0xFFFFu));
        a1y += v1 * bf16_to_f32((ushort)(p1 >> 16));
        a2x += v2 * bf16_to_f32((ushort)(p2 & 0xFFFFu));
        a2y += v2 * bf16_to_f32((ushort)(p2 >> 16));
        a3x += v3 * bf16_to_f32((ushort)(p3 & 0xFFFFu));
        a3y += v3 * bf16_to_f32((ushort)(p3 >> 16));
      }
      for (; j < je; j += 2) {
        const uint src = s_src[j];
        const float v = bf16_to_f32(s_val[j]);
        const uint p = *(const uint*)&pre16[(size_t)src * D_OUT + 2 * hl];
        a0x += v * bf16_to_f32((ushort)(p & 0xFFFFu));
        a0y += v * bf16_to_f32((ushort)(p >> 16));
      }
      float ax = ((a0x + a1x) + (a2x + a3x)) + ((a4x + a5x) + (a6x + a7x));
      float ay = ((a0y + a1y) + (a2y + a3y)) + ((a4y + a5y) + (a6y + a7y));
      ax += __shfl_xor(ax, 32);   // merge odd-record half into even half
      ay += __shfl_xor(ay, 32);
      if (half == 0) {
        *(float2*)&out[(size_t)node * D_OUT + 2 * hl] = make_float2(ax, ay);
        csx += ax;
        cs2x += ax * ax;
        csy += ay;
        cs2y += ay * ay;
      }
    }
  }
  __syncthreads();  // record reads done; alias reduction buffers onto s_src

  float* red = (float*)s_src;       // [8 waves][64 cols] sums (2 KB)
  float* red2 = red + 512;          // [8 waves][64 cols] sumsq (2 KB)
  if (half == 0) {
    red[wave * 64 + 2 * hl] = csx;
    red[wave * 64 + 2 * hl + 1] = csy;
    red2[wave * 64 + 2 * hl] = cs2x;
    red2[wave * 64 + 2 * hl + 1] = cs2y;
  }
  __syncthreads();
  if (t < 64) {
    float s = 0.f, s2 = 0.f;
#pragma unroll
    for (int wv = 0; wv < 8; ++wv) {
      s += red[wv * 64 + t];
      s2 += red2[wv * 64 + t];
    }
    atomicAdd(&stats[t], s);
    atomicAdd(&stats[64 + t], s2);
  }
}

// ---------------- Normalize + ReLU (in place, float4) ----------------
__global__ __launch_bounds__(256) void norm_kernel(
    float* __restrict__ out, const float* __restrict__ stats, int64_t n_vec4,
    float inv_n) {
  const int c = (threadIdx.x * 4) & 63;
  float mean[4], scale[4];
#pragma unroll
  for (int k = 0; k < 4; ++k) {
    mean[k] = stats[c + k] * inv_n;
    const float var = stats[64 + c + k] * inv_n - mean[k] * mean[k];
    scale[k] = rsqrtf(var + BN_EPS);
  }
  const int64_t stride = (int64_t)gridDim.x * 256;
  for (int64_t i = (int64_t)blockIdx.x * 256 + threadIdx.x; i < n_vec4;
       i += stride) {
    float4 v = ((float4*)out)[i];
    v.x = (v.x - mean[0]) * scale[0];
    v.y = (v.y - mean[1]) * scale[1];
    v.z = (v.z - mean[2]) * scale[2];
    v.w = (v.w - mean[3]) * scale[3];
    v.x = v.x > 0.f ? v.x : 0.f;
    v.y = v.y > 0.f ? v.y : 0.f;
    v.z = v.z > 0.f ? v.z : 0.f;
    v.w = v.w > 0.f ? v.w : 0.f;
    ((float4*)out)[i] = v;
  }
}

// ---------------- launch: 4 dispatches total ----------------
extern "C" void kernel_launch(void* const* d_in, const int* in_sizes, int n_in,
                              void* d_out, int out_size, void* d_ws,
                              size_t ws_size, hipStream_t stream) {
  const float* x = (const float*)d_in[0];
  const float* W = (const float*)d_in[1];
  const float* ev = (const float*)d_in[2];
  const int* esrc = (const int*)d_in[3];
  const int* edst = (const int*)d_in[4];

  const int n_nodes = in_sizes[0] / D_IN;
  const int n_edges = in_sizes[2];
  const int64_t n_out = (int64_t)n_nodes * D_OUT;
  const int n_bins = (n_nodes + BIN_NODES - 1) >> BIN_SHIFT;
  const int n_row_tiles = (n_nodes + 63) / 64;
  const int n_chunks = (n_edges + CHUNK - 1) / CHUNK;

  float* out = (float*)d_out;

  // workspace layout (~40 MB total, under prior peaks)
  char* w = (char*)d_ws;
  ushort* pre16 = (ushort*)w;             w += (size_t)n_nodes * D_OUT * 2;
  float* stats = (float*)w;               w += 128 * 4;
  int* loff_g = (int*)w;                  w += (size_t)n_chunks * LOFF_STRIDE * 4;
  w = (char*)(((uintptr_t)w + 7) & ~(uintptr_t)7);
  uint2* bucket = (uint2*)w;              // n_edges * 8 bytes (25.6 MB, exact)

  gemm_mfma_kernel<<<n_row_tiles, 256, 0, stream>>>(
      x, W, pre16, stats, n_nodes, n_row_tiles);
  partition_kernel<<<n_chunks, 1024, 0, stream>>>(ev, esrc, edst, loff_g,
                                                  bucket, n_edges, n_bins);
  bin_sort_gather_kernel<<<n_bins, 512, 0, stream>>>(
      pre16, bucket, loff_g, out, stats, n_nodes, n_chunks, n_bins);
  norm_kernel<<<2048, 256, 0, stream>>>(out, stats, n_out / 4,
                                        1.0f / (float)n_nodes);
}

// Round 13
// 281.647 us; speedup vs baseline: 1.0418x; 1.0112x over previous
//
#include <hip/hip_runtime.h>
#include <stdint.h>

#define D_IN  128
#define D_OUT 64
#define BN_EPS 1e-3f

#define BIN_SHIFT 7
#define BIN_NODES 128          // 1 << BIN_SHIFT
#define BIN_CAP   5120         // per-bin segment capacity (mean 4096, +16 sigma)
#define CHUNK     8192         // edges per partition block (391 blocks)
#define MAX_BINS  800
#define LOFF_STRIDE 800        // ints per chunk row in cnt/goff tables
#define PT_STRIDE 72           // ushorts: gemm epilogue LDS row stride

typedef __attribute__((ext_vector_type(8))) short bf16x8;
typedef __attribute__((ext_vector_type(4))) float f32x4;

__device__ __forceinline__ ushort f32_to_bf16_rne(float f) {
  uint u = __float_as_uint(f);
  u += 0x7FFFu + ((u >> 16) & 1u);
  return (ushort)(u >> 16);
}
__device__ __forceinline__ float bf16_to_f32(ushort h) {
  return __uint_as_float((uint)h << 16);
}

// ------------- GEMM via MFMA: pre16 = bf16(X @ W), bf16 in / fp32 acc -------
// Row-major pre16[row][64ch]: one node = one 128-B cache line (load-bearing
// for the gather; r1: slab layouts over-fetch 4x on random access).
// Epilogue staged through LDS -> full 128-B line stores. Block 0 zeroes stats.
__global__ __launch_bounds__(256) void gemm_mfma_kernel(
    const float* __restrict__ x, const float* __restrict__ W,
    ushort* __restrict__ pre16, float* __restrict__ stats,
    int n_nodes, int n_tiles) {
  __shared__ ushort Wb[D_IN * D_OUT];          // 16 KB bf16 copy of W
  __shared__ ushort ptile[64 * PT_STRIDE];     // 9 KB epilogue staging
  const int t = threadIdx.x;
  if (blockIdx.x == 0 && t < 128) stats[t] = 0.f;
  for (int i = t; i < D_IN * D_OUT; i += 256) Wb[i] = f32_to_bf16_rne(W[i]);
  __syncthreads();

  const int lane = t & 63;
  const int wave = t >> 6;
  const int m = lane & 15;
  const int quad = lane >> 4;

  bf16x8 bfrag[4][4];
#pragma unroll
  for (int nt = 0; nt < 4; ++nt)
#pragma unroll
    for (int s = 0; s < 4; ++s)
#pragma unroll
      for (int j = 0; j < 8; ++j)
        bfrag[nt][s][j] =
            (short)Wb[(32 * s + quad * 8 + j) * D_OUT + nt * 16 + m];

  for (int tile = blockIdx.x; tile < n_tiles; tile += gridDim.x) {
    const int rbase0 = tile * 64;
    const int row = rbase0 + wave * 16 + m;
    const size_t rl = (size_t)min(row, n_nodes - 1);
    f32x4 acc0 = {0.f, 0.f, 0.f, 0.f}, acc1 = {0.f, 0.f, 0.f, 0.f};
    f32x4 acc2 = {0.f, 0.f, 0.f, 0.f}, acc3 = {0.f, 0.f, 0.f, 0.f};
#pragma unroll
    for (int s = 0; s < 4; ++s) {
      const float4 xa = *(const float4*)&x[rl * D_IN + s * 32 + quad * 8];
      const float4 xb = *(const float4*)&x[rl * D_IN + s * 32 + quad * 8 + 4];
      bf16x8 af;
      af[0] = (short)f32_to_bf16_rne(xa.x);
      af[1] = (short)f32_to_bf16_rne(xa.y);
      af[2] = (short)f32_to_bf16_rne(xa.z);
      af[3] = (short)f32_to_bf16_rne(xa.w);
      af[4] = (short)f32_to_bf16_rne(xb.x);
      af[5] = (short)f32_to_bf16_rne(xb.y);
      af[6] = (short)f32_to_bf16_rne(xb.z);
      af[7] = (short)f32_to_bf16_rne(xb.w);
      acc0 = __builtin_amdgcn_mfma_f32_16x16x32_bf16(af, bfrag[0][s], acc0, 0, 0, 0);
      acc1 = __builtin_amdgcn_mfma_f32_16x16x32_bf16(af, bfrag[1][s], acc1, 0, 0, 0);
      acc2 = __builtin_amdgcn_mfma_f32_16x16x32_bf16(af, bfrag[2][s], acc2, 0, 0, 0);
      acc3 = __builtin_amdgcn_mfma_f32_16x16x32_bf16(af, bfrag[3][s], acc3, 0, 0, 0);
    }
    __syncthreads();  // previous tile's ptile reads complete
#pragma unroll
    for (int reg = 0; reg < 4; ++reg) {
      const int lr = wave * 16 + quad * 4 + reg;
      ptile[lr * PT_STRIDE + m]      = f32_to_bf16_rne(acc0[reg]);
      ptile[lr * PT_STRIDE + 16 + m] = f32_to_bf16_rne(acc1[reg]);
      ptile[lr * PT_STRIDE + 32 + m] = f32_to_bf16_rne(acc2[reg]);
      ptile[lr * PT_STRIDE + 48 + m] = f32_to_bf16_rne(acc3[reg]);
    }
    __syncthreads();
    // cooperative write-out: 4 threads per row, 32 B each -> 128-B lines
    {
      const int lr = t >> 2;
      const int sg = t & 3;
      const int r = rbase0 + lr;
      if (r < n_nodes) {
        const uint4* pl = (const uint4*)&ptile[lr * PT_STRIDE + sg * 16];
        uint4* po = (uint4*)&pre16[(size_t)r * D_OUT + sg * 16];
        po[0] = pl[0];
        po[1] = pl[1];
      }
    }
  }
}

// ---- P1: per-chunk histogram by bin (no scatter) ----------------------------
// r13 exact-placement scheme: r10's global-cursor partition paid 391-deep
// atomic chains; r12's block-local layout paid run-walk gather fragmentation
// (FETCH 155->207 MB, gather +12 us). Replacing reservation with a
// precomputed cross-chunk scan kills both: no global atomics AND a dense,
// contiguous-per-bin bucket.
__global__ __launch_bounds__(1024) void part_hist_kernel(
    const int* __restrict__ edst, int* __restrict__ cnt_g, int n_edges,
    int n_bins) {
  __shared__ int cnt[MAX_BINS];
  const int t = threadIdx.x;
  const int beg = blockIdx.x * CHUNK;
  const int end = min(beg + CHUNK, n_edges);

  for (int i = t; i < n_bins; i += 1024) cnt[i] = 0;
  __syncthreads();

  for (int i = beg + t * 4; i < end; i += 4096) {
    if (i + 3 < end) {
      const int4 d4 = *(const int4*)&edst[i];
      atomicAdd(&cnt[d4.x >> BIN_SHIFT], 1);
      atomicAdd(&cnt[d4.y >> BIN_SHIFT], 1);
      atomicAdd(&cnt[d4.z >> BIN_SHIFT], 1);
      atomicAdd(&cnt[d4.w >> BIN_SHIFT], 1);
    } else {
      for (int k = i; k < end; ++k) atomicAdd(&cnt[edst[k] >> BIN_SHIFT], 1);
    }
  }
  __syncthreads();

  for (int i = t; i < n_bins; i += 1024)
    cnt_g[blockIdx.x * LOFF_STRIDE + i] = cnt[i];  // coalesced row
}

// ---- P2: per-bin cross-chunk exclusive scan ---------------------------------
// Block b scans the 391-element column cnt_g[*][b] -> goff[c][b] = exact slot
// of chunk c's bin-b run inside segment [b*BIN_CAP, ...). Table is 1.25 MB:
// column reads/writes are scattered but L2/L3-cached (read by 782 small
// blocks). bin_total[b] = clamped segment fill for the gather.
__global__ __launch_bounds__(512) void part_scan_kernel(
    const int* __restrict__ cnt_g, int* __restrict__ goff,
    int* __restrict__ bin_total, int n_chunks) {
  __shared__ int sdata[512];
  const int b = blockIdx.x;
  const int t = threadIdx.x;
  const int v = (t < n_chunks) ? cnt_g[t * LOFF_STRIDE + b] : 0;
  sdata[t] = v;
  __syncthreads();
  for (int off = 1; off < 512; off <<= 1) {
    const int u = (t >= off) ? sdata[t - off] : 0;
    __syncthreads();
    sdata[t] += u;
    __syncthreads();
  }
  if (t < n_chunks) goff[t * LOFF_STRIDE + b] = sdata[t] - v;
  if (t == n_chunks - 1) bin_total[b] = min(sdata[t], BIN_CAP);
}

// ---- P3: scatter to exact final positions -----------------------------------
// Each run (avg 10.5 records) lands contiguously at its precomputed slot;
// adjacent chunks' runs are adjacent -> bucket is dense and bin-sorted.
// Only LDS atomics (rank cursors); partial-line sharing only at run
// boundaries (~1.5x amp vs r9's 3.2x interleave).
__global__ __launch_bounds__(1024) void part_scatter_kernel(
    const float* __restrict__ ev, const int* __restrict__ esrc,
    const int* __restrict__ edst, const int* __restrict__ goff,
    uint2* __restrict__ bucket, int n_edges, int n_bins) {
  __shared__ int cnt[MAX_BINS];
  __shared__ int base[MAX_BINS];
  const int t = threadIdx.x;
  const int beg = blockIdx.x * CHUNK;
  const int end = min(beg + CHUNK, n_edges);

  for (int i = t; i < n_bins; i += 1024) {
    cnt[i] = 0;
    base[i] = i * BIN_CAP + goff[blockIdx.x * LOFF_STRIDE + i];  // coalesced
  }
  __syncthreads();

  for (int i = beg + t * 4; i < end; i += 4096) {
    if (i + 3 < end) {
      const int4 d4 = *(const int4*)&edst[i];
      const int4 s4 = *(const int4*)&esrc[i];
      const float4 v4 = *(const float4*)&ev[i];
#pragma unroll
      for (int k = 0; k < 4; ++k) {
        const int dst = (&d4.x)[k];
        const int bin = dst >> BIN_SHIFT;
        const int r = atomicAdd(&cnt[bin], 1);
        const int pos = base[bin] + r;
        if (pos < (bin + 1) * BIN_CAP) {
          const uint w0 =
              ((uint)(dst & (BIN_NODES - 1)) << 17) | (uint)(&s4.x)[k];
          bucket[pos] = make_uint2(w0, __float_as_uint((&v4.x)[k]));
        }
      }
    } else {
      for (int k = i; k < end; ++k) {
        const int dst = edst[k];
        const int bin = dst >> BIN_SHIFT;
        const int r = atomicAdd(&cnt[bin], 1);
        const int pos = base[bin] + r;
        if (pos < (bin + 1) * BIN_CAP) {
          const uint w0 = ((uint)(dst & (BIN_NODES - 1)) << 17) | (uint)esrc[k];
          bucket[pos] = make_uint2(w0, __float_as_uint(ev[k]));
        }
      }
    }
  }
}

// ------- Bin sort+gather: contiguous segment reads (r10's proven form) -------
// Segment [bin*BIN_CAP, +bin_total) is dense and contiguous: histogram pass
// streams it, scatter pass re-reads its own 32-KB segment L2-hot. Gather core
// unchanged (r8 lesson). Gather duration tracks FETCH_SIZE / ~1.9 TB/s
// (r4/r12 evidence) -> contiguity is the lever: 207 -> ~160 MB.
__global__ __launch_bounds__(512) void bin_sort_gather_kernel(
    const ushort* __restrict__ pre16, const uint2* __restrict__ bucket,
    const int* __restrict__ bin_total, float* __restrict__ out,
    float* __restrict__ stats, int n_nodes) {
  __shared__ uint s_src[BIN_CAP];          // 20.0 KB
  __shared__ ushort s_val[BIN_CAP];        // 10.0 KB
  __shared__ int s_hist[BIN_NODES];
  __shared__ int s_off[BIN_NODES + 1];
  __shared__ int s_cur[BIN_NODES];

  const int t = threadIdx.x;
  const int bin = blockIdx.x;
  const int cnt = bin_total[bin];          // pre-clamped <= BIN_CAP
  const int64_t rbase = (int64_t)bin * BIN_CAP;

  if (t < BIN_NODES) s_hist[t] = 0;
  __syncthreads();

  for (int i = t; i < cnt; i += 512)
    atomicAdd(&s_hist[bucket[rbase + i].x >> 17], 1);
  __syncthreads();

  int own = (t < BIN_NODES) ? s_hist[t] : 0;
  for (int off = 1; off < BIN_NODES; off <<= 1) {
    int u = 0;
    if (t < BIN_NODES && t >= off) u = s_hist[t - off];
    __syncthreads();
    if (t < BIN_NODES) s_hist[t] += u;
    __syncthreads();
  }
  if (t < BIN_NODES) {
    const int e = s_hist[t] - own;
    s_off[t] = e;
    s_cur[t] = e;
  }
  if (t == 0) s_off[BIN_NODES] = cnt;
  __syncthreads();

  for (int i = t; i < cnt; i += 512) {
    const uint2 r = bucket[rbase + i];
    const int d = r.x >> 17;
    const int p = atomicAdd(&s_cur[d], 1);
    s_src[p] = r.x & 0x1FFFFu;
    s_val[p] = f32_to_bf16_rne(__uint_as_float(r.y));
  }
  __syncthreads();

  // gather: wave per node (8 waves); half-waves on even/odd records;
  // 8 records/half in flight in main loop. UNCHANGED.
  const int lane = t & 63;
  const int wave = t >> 6;
  const int half = lane >> 5;
  const int hl = lane & 31;
  const int node0 = bin * BIN_NODES;
  float csx = 0.f, csy = 0.f, cs2x = 0.f, cs2y = 0.f;

  for (int nl = wave; nl < BIN_NODES; nl += 8) {
    const int node = node0 + nl;
    if (node < n_nodes) {
      const int jb = s_off[nl], je = s_off[nl + 1];
      float a0x = 0.f, a0y = 0.f, a1x = 0.f, a1y = 0.f;
      float a2x = 0.f, a2y = 0.f, a3x = 0.f, a3y = 0.f;
      float a4x = 0.f, a4y = 0.f, a5x = 0.f, a5y = 0.f;
      float a6x = 0.f, a6y = 0.f, a7x = 0.f, a7y = 0.f;
      int j = jb + half;
      // main: 16 records per wave-iteration, 8 loads in flight per half
      for (; j + 14 < je; j += 16) {
        const uint src0 = s_src[j],      src1 = s_src[j + 2];
        const uint src2 = s_src[j + 4],  src3 = s_src[j + 6];
        const uint src4 = s_src[j + 8],  src5 = s_src[j + 10];
        const uint src6 = s_src[j + 12], src7 = s_src[j + 14];
        const float v0 = bf16_to_f32(s_val[j]);
        const float v1 = bf16_to_f32(s_val[j + 2]);
        const float v2 = bf16_to_f32(s_val[j + 4]);
        const float v3 = bf16_to_f32(s_val[j + 6]);
        const float v4 = bf16_to_f32(s_val[j + 8]);
        const float v5 = bf16_to_f32(s_val[j + 10]);
        const float v6 = bf16_to_f32(s_val[j + 12]);
        const float v7 = bf16_to_f32(s_val[j + 14]);
        const uint p0 = *(const uint*)&pre16[(size_t)src0 * D_OUT + 2 * hl];
        const uint p1 = *(const uint*)&pre16[(size_t)src1 * D_OUT + 2 * hl];
        const uint p2 = *(const uint*)&pre16[(size_t)src2 * D_OUT + 2 * hl];
        const uint p3 = *(const uint*)&pre16[(size_t)src3 * D_OUT + 2 * hl];
        const uint p4 = *(const uint*)&pre16[(size_t)src4 * D_OUT + 2 * hl];
        const uint p5 = *(const uint*)&pre16[(size_t)src5 * D_OUT + 2 * hl];
        const uint p6 = *(const uint*)&pre16[(size_t)src6 * D_OUT + 2 * hl];
        const uint p7 = *(const uint*)&pre16[(size_t)src7 * D_OUT + 2 * hl];
        a0x += v0 * bf16_to_f32((ushort)(p0 & 0xFFFFu));
        a0y += v0 * bf16_to_f32((ushort)(p0 >> 16));
        a1x += v1 * bf16_to_f32((ushort)(p1 & 0xFFFFu));
        a1y += v1 * bf16_to_f32((ushort)(p1 >> 16));
        a2x += v2 * bf16_to_f32((ushort)(p2 & 0xFFFFu));
        a2y += v2 * bf16_to_f32((ushort)(p2 >> 16));
        a3x += v3 * bf16_to_f32((ushort)(p3 & 0xFFFFu));
        a3y += v3 * bf16_to_f32((ushort)(p3 >> 16));
        a4x += v4 * bf16_to_f32((ushort)(p4 & 0xFFFFu));
        a4y += v4 * bf16_to_f32((ushort)(p4 >> 16));
        a5x += v5 * bf16_to_f32((ushort)(p5 & 0xFFFFu));
        a5y += v5 * bf16_to_f32((ushort)(p5 >> 16));
        a6x += v6 * bf16_to_f32((ushort)(p6 & 0xFFFFu));
        a6y += v6 * bf16_to_f32((ushort)(p6 >> 16));
        a7x += v7 * bf16_to_f32((ushort)(p7 & 0xFFFFu));
        a7y += v7 * bf16_to_f32((ushort)(p7 >> 16));
      }
      // mid: 8 records per wave-iteration
      for (; j + 6 < je; j += 8) {
        const uint src0 = s_src[j],     src1 = s_src[j + 2];
        const uint src2 = s_src[j + 4], src3 = s_src[j + 6];
        const float v0 = bf16_to_f32(s_val[j]);
        const float v1 = bf16_to_f32(s_val[j + 2]);
        const float v2 = bf16_to_f32(s_val[j + 4]);
        const float v3 = bf16_to_f32(s_val[j + 6]);
        const uint p0 = *(const uint*)&pre16[(size_t)src0 * D_OUT + 2 * hl];
        const uint p1 = *(const uint*)&pre16[(size_t)src1 * D_OUT + 2 * hl];
        const uint p2 = *(const uint*)&pre16[(size_t)src2 * D_OUT + 2 * hl];
        const uint p3 = *(const uint*)&pre16[(size_t)src3 * D_OUT + 2 * hl];
        a0x += v0 * bf16_to_f32((ushort)(p0 & 0xFFFFu));
        a0y += v0 * bf16_to_f32((ushort)(p0 >> 16));
        a1x += v1 * bf16_to_f32((ushort)(p1 & 0xFFFFu));
        a1y += v1 * bf16_to_f32((ushort)(p1 >> 16));
        a2x += v2 * bf16_to_f32((ushort)(p2 & 0xFFFFu));
        a2y += v2 * bf16_to_f32((ushort)(p2 >> 16));
        a3x += v3 * bf16_to_f32((ushort)(p3 & 0xFFFFu));
        a3y += v3 * bf16_to_f32((ushort)(p3 >> 16));
      }
      for (; j < je; j += 2) {
        const uint src = s_src[j];
        const float v = bf16_to_f32(s_val[j]);
        const uint p = *(const uint*)&pre16[(size_t)src * D_OUT + 2 * hl];
        a0x += v * bf16_to_f32((ushort)(p & 0xFFFFu));
        a0y += v * bf16_to_f32((ushort)(p >> 16));
      }
      float ax = ((a0x + a1x) + (a2x + a3x)) + ((a4x + a5x) + (a6x + a7x));
      float ay = ((a0y + a1y) + (a2y + a3y)) + ((a4y + a5y) + (a6y + a7y));
      ax += __shfl_xor(ax, 32);   // merge odd-record half into even half
      ay += __shfl_xor(ay, 32);
      if (half == 0) {
        *(float2*)&out[(size_t)node * D_OUT + 2 * hl] = make_float2(ax, ay);
        csx += ax;
        cs2x += ax * ax;
        csy += ay;
        cs2y += ay * ay;
      }
    }
  }
  __syncthreads();  // record reads done; alias reduction buffers onto s_src

  float* red = (float*)s_src;       // [8 waves][64 cols] sums (2 KB)
  float* red2 = red + 512;          // [8 waves][64 cols] sumsq (2 KB)
  if (half == 0) {
    red[wave * 64 + 2 * hl] = csx;
    red[wave * 64 + 2 * hl + 1] = csy;
    red2[wave * 64 + 2 * hl] = cs2x;
    red2[wave * 64 + 2 * hl + 1] = cs2y;
  }
  __syncthreads();
  if (t < 64) {
    float s = 0.f, s2 = 0.f;
#pragma unroll
    for (int wv = 0; wv < 8; ++wv) {
      s += red[wv * 64 + t];
      s2 += red2[wv * 64 + t];
    }
    atomicAdd(&stats[t], s);
    atomicAdd(&stats[64 + t], s2);
  }
}

// ---------------- Normalize + ReLU (in place, float4) ----------------
__global__ __launch_bounds__(256) void norm_kernel(
    float* __restrict__ out, const float* __restrict__ stats, int64_t n_vec4,
    float inv_n) {
  const int c = (threadIdx.x * 4) & 63;
  float mean[4], scale[4];
#pragma unroll
  for (int k = 0; k < 4; ++k) {
    mean[k] = stats[c + k] * inv_n;
    const float var = stats[64 + c + k] * inv_n - mean[k] * mean[k];
    scale[k] = rsqrtf(var + BN_EPS);
  }
  const int64_t stride = (int64_t)gridDim.x * 256;
  for (int64_t i = (int64_t)blockIdx.x * 256 + threadIdx.x; i < n_vec4;
       i += stride) {
    float4 v = ((float4*)out)[i];
    v.x = (v.x - mean[0]) * scale[0];
    v.y = (v.y - mean[1]) * scale[1];
    v.z = (v.z - mean[2]) * scale[2];
    v.w = (v.w - mean[3]) * scale[3];
    v.x = v.x > 0.f ? v.x : 0.f;
    v.y = v.y > 0.f ? v.y : 0.f;
    v.z = v.z > 0.f ? v.z : 0.f;
    v.w = v.w > 0.f ? v.w : 0.f;
    ((float4*)out)[i] = v;
  }
}

// ---------------- launch: 6 dispatches total ----------------
extern "C" void kernel_launch(void* const* d_in, const int* in_sizes, int n_in,
                              void* d_out, int out_size, void* d_ws,
                              size_t ws_size, hipStream_t stream) {
  const float* x = (const float*)d_in[0];
  const float* W = (const float*)d_in[1];
  const float* ev = (const float*)d_in[2];
  const int* esrc = (const int*)d_in[3];
  const int* edst = (const int*)d_in[4];

  const int n_nodes = in_sizes[0] / D_IN;
  const int n_edges = in_sizes[2];
  const int64_t n_out = (int64_t)n_nodes * D_OUT;
  const int n_bins = (n_nodes + BIN_NODES - 1) >> BIN_SHIFT;
  const int n_row_tiles = (n_nodes + 63) / 64;
  const int n_chunks = (n_edges + CHUNK - 1) / CHUNK;

  float* out = (float*)d_out;

  // workspace layout (~47 MB)
  char* w = (char*)d_ws;
  ushort* pre16 = (ushort*)w;             w += (size_t)n_nodes * D_OUT * 2;
  float* stats = (float*)w;               w += 128 * 4;
  int* cnt_g = (int*)w;                   w += (size_t)n_chunks * LOFF_STRIDE * 4;
  int* goff = (int*)w;                    w += (size_t)n_chunks * LOFF_STRIDE * 4;
  int* bin_total = (int*)w;               w += (size_t)n_bins * 4;
  w = (char*)(((uintptr_t)w + 7) & ~(uintptr_t)7);
  uint2* bucket = (uint2*)w;              // n_bins * BIN_CAP * 8 (~32 MB)

  gemm_mfma_kernel<<<n_row_tiles, 256, 0, stream>>>(
      x, W, pre16, stats, n_nodes, n_row_tiles);
  part_hist_kernel<<<n_chunks, 1024, 0, stream>>>(edst, cnt_g, n_edges,
                                                  n_bins);
  part_scan_kernel<<<n_bins, 512, 0, stream>>>(cnt_g, goff, bin_total,
                                               n_chunks);
  part_scatter_kernel<<<n_chunks, 1024, 0, stream>>>(ev, esrc, edst, goff,
                                                     bucket, n_edges, n_bins);
  bin_sort_gather_kernel<<<n_bins, 512, 0, stream>>>(pre16, bucket, bin_total,
                                                     out, stats, n_nodes);
  norm_kernel<<<2048, 256, 0, stream>>>(out, stats, n_out / 4,
                                        1.0f / (float)n_nodes);
}